// Round 8
// baseline (551.815 us; speedup 1.0000x reference)
//
#include <hip/hip_runtime.h>
#include <hip/hip_bf16.h>
#include <stdint.h>

#define NN 50000
#define EE 800000
#define HD 64
#define AGS 72   // aggf row stride: 64 feats + 3 trans + pad

typedef short short8 __attribute__((ext_vector_type(8)));
typedef float f32x4  __attribute__((ext_vector_type(4)));
typedef float f32x16 __attribute__((ext_vector_type(16)));
typedef uint  uint2v __attribute__((ext_vector_type(2)));

__device__ __forceinline__ float b2f(ushort u){ return __uint_as_float(((uint32_t)u)<<16); }
__device__ __forceinline__ ushort f2b(float f){
  uint32_t u = __float_as_uint(f);
  u += 0x7fffu + ((u>>16)&1u);
  return (ushort)(u>>16);
}
__device__ __forceinline__ uint pk2(float lo, float hi){
  union { __hip_bfloat162 b; uint u; } x;
  x.b = __float22bfloat162_rn(make_float2(lo, hi));
  return x.u;
}
__device__ __forceinline__ float silu_f(float x){
  return x * __builtin_amdgcn_rcpf(1.0f + __expf(-x));
}

// ---------------- prep kernels ----------------

// merged: edge-count atomics + node init (speed0 folded into velw4.w)
__global__ __launch_bounds__(256) void k_count2(const int* __restrict__ erow,
    int* __restrict__ counts, const float* __restrict__ loc,
    const float* __restrict__ vel0, float4* __restrict__ coordw4,
    float4* __restrict__ velw4){
  int gid = blockIdx.x*256 + threadIdx.x;
  if (gid < EE) atomicAdd(&counts[erow[gid]], 1);
  if (gid < NN){
    float vx = vel0[gid*3+0], vy = vel0[gid*3+1], vz = vel0[gid*3+2];
    float sp = sqrtf(vx*vx + vy*vy + vz*vz);
    velw4[gid] = make_float4(vx, vy, vz, sp);
    coordw4[gid] = make_float4(loc[gid*3+0], loc[gid*3+1], loc[gid*3+2], 0.0f);
  }
}

__global__ __launch_bounds__(256) void k_bsum(const int* __restrict__ counts, int* __restrict__ bsum){
  __shared__ int sm[4];
  int tid = threadIdx.x;
  int i = blockIdx.x*256 + tid;
  int v = (i < NN) ? counts[i] : 0;
  #pragma unroll
  for (int off = 1; off < 64; off <<= 1) v += __shfl_xor(v, off);
  if ((tid & 63) == 0) sm[tid >> 6] = v;
  __syncthreads();
  if (tid == 0) bsum[blockIdx.x] = sm[0] + sm[1] + sm[2] + sm[3];
}

__global__ __launch_bounds__(256) void k_bscan(const int* __restrict__ bsum, int* __restrict__ bbase){
  __shared__ int sm[256];
  int tid = threadIdx.x;
  int v = (tid < 196) ? bsum[tid] : 0;
  sm[tid] = v;
  __syncthreads();
  #pragma unroll
  for (int off = 1; off < 256; off <<= 1){
    int t = (tid >= off) ? sm[tid - off] : 0;
    __syncthreads();
    sm[tid] += t;
    __syncthreads();
  }
  if (tid < 196) bbase[tid] = sm[tid] - v;   // exclusive
}

__global__ __launch_bounds__(256) void k_scatter(const int* __restrict__ counts,
    const int* __restrict__ bbase, int* __restrict__ cursor){
  __shared__ int sm[256];
  int tid = threadIdx.x;
  int i = blockIdx.x*256 + tid;
  int v = (i < NN) ? counts[i] : 0;
  sm[tid] = v;
  __syncthreads();
  #pragma unroll
  for (int off = 1; off < 256; off <<= 1){
    int t = (tid >= off) ? sm[tid - off] : 0;
    __syncthreads();
    sm[tid] += t;
    __syncthreads();
  }
  if (i < NN) cursor[i] = bbase[blockIdx.x] + sm[tid] - v;
}

// build CSR-sorted edge records {row, col, ea0, ea1}
__global__ __launch_bounds__(256) void k_fill(const int* __restrict__ erow,
    const int* __restrict__ ecol, const float* __restrict__ eattr,
    int* __restrict__ cursor, int4* __restrict__ erec){
  int e = blockIdx.x*256 + threadIdx.x;
  if (e < EE){
    int r = erow[e];
    int pos = atomicAdd(&cursor[r], 1);
    int4 rec;
    rec.x = r;
    rec.y = ecol[e];
    rec.z = __float_as_int(eattr[(size_t)e*2 + 0]);
    rec.w = __float_as_int(eattr[(size_t)e*2 + 1]);
    erec[pos] = rec;
  }
}

// pack weights.
// Edge weights, 32x32x16 frag order: unit (kt,mt) of 512 elems; elem (lane,i):
//   W1 (identity k): k = kt*16 + (lane>>5)*8 + i
//   W2/cW1 (pi-permuted k to match D-layout->pk2 register order of the previous GEMM):
//   k = 32*(kt>>1) + 16*(kt&1) + 8*(i>>2) + 2*((i>>1)&1) + (i&1) + 4*(lane>>5)
//   col = mt*32 + (lane&31)
// eW1 K=144 (9 kt): k<131 -> eW1 ; k==131 -> b1 ; else 0
// Node weights in 16x16x32 frag order (unchanged).
__global__ __launch_bounds__(256) void k_packall(const float* __restrict__ eW1,
    const float* __restrict__ b1, const float* __restrict__ eW2,
    const float* __restrict__ cW1, const float* __restrict__ nW1,
    const float* __restrict__ nW2, const float* __restrict__ vW1,
    ushort* __restrict__ dst){
  int idx = blockIdx.x*256 + threadIdx.x;
  if (idx >= 33792) return;
  float v;
  if (idx < 17408){
    int rel; const float* src; int isW1 = 0;
    if (idx < 9216){ rel = idx; src = eW1; isW1 = 1; }
    else if (idx < 13312){ rel = idx - 9216; src = eW2; }
    else { rel = idx - 13312; src = cW1; }
    int u = rel >> 9;           // (kt*2+mt)
    int kt = u >> 1, mt = u & 1;
    int within = rel & 511;
    int lane = within >> 3, i = within & 7;
    int col = mt*32 + (lane & 31);
    if (isW1){
      int k = kt*16 + (lane>>5)*8 + i;
      if (k < 131) v = src[k*64 + col];
      else if (k == 131) v = b1[col];
      else v = 0.0f;
    } else {
      int k = 32*(kt>>1) + 16*(kt&1) + 8*(i>>2) + 2*((i>>1)&1) + (i&1) + 4*(lane>>5);
      v = src[k*64 + col];
    }
  } else {
    int rel = idx - 17408;
    const float* src; int kt; int Ksrc;
    if (rel < 8192){ src = nW1; kt = rel >> 11; Ksrc = 128; }
    else if (rel < 12288){ src = nW2; kt = (rel - 8192) >> 11; Ksrc = 64; }
    else { src = vW1; kt = (rel - 12288) >> 11; Ksrc = 64; }
    int within = rel & 2047;
    int i = within & 7;
    int lane = (within >> 3) & 63;
    int ct = (within >> 9) & 3;
    int k = kt*32 + (lane>>4)*8 + i;
    int col = ct*16 + (lane & 15);
    v = (k < Ksrc) ? src[k*64 + col] : 0.0f;
  }
  dst[idx] = f2b(v);
}

__global__ __launch_bounds__(256) void k_embed(const float* __restrict__ his,
    const float* __restrict__ embW, const float* __restrict__ embB,
    float* __restrict__ h, ushort* __restrict__ hb){
  int idx = blockIdx.x*256 + threadIdx.x;
  if (idx >= NN*HD) return;
  int n = idx >> 6, j = idx & 63;
  float s = embB[j];
  #pragma unroll
  for (int k = 0; k < 8; ++k) s += his[n*8 + k] * embW[k*64 + j];
  h[idx] = s;
  hb[idx] = f2b(s);
}

// ---------------- edge MFMA kernel: 32x32x16, all-swapped, register-chained ----------------
// Per wave: 32 edges (e = lane&31), h = lane>>5.
// D = W^T·X^T ; lane(e,h) reg r of mt-tile = X[e][feat mt*32 + (r&3)+8*(r>>2)+4h].
// pk2 register packing: uw[mt*8+s] = (feat F, F+1), F = 2(s&1)+8(s>>1)+4h+32mt.
// W2/cW1 are pi-packed so B-frag of the next GEMM = uw words [4kt..4kt+3] DIRECTLY
// (k-permutation cancels between A and B). No LDS on the GEMM chain.
// LDS only for the segmented sum: m row per edge = 32 uints, stride 34.
__global__ __launch_bounds__(256, 4) void k_edge(
    const ushort* __restrict__ hb, const float4* __restrict__ coord4,
    const int4* __restrict__ erec,
    const ushort* __restrict__ W1p, const ushort* __restrict__ W2p, const ushort* __restrict__ C1p,
    const float* __restrict__ b2, const float* __restrict__ cb1, const float* __restrict__ cw2,
    float* __restrict__ aggf)
{
  __shared__ __align__(16) uint XMT[128*34];
  __shared__ __align__(16) float TRL[128*4];
  const int tid = threadIdx.x;
  const int wave = tid >> 6, lane = tid & 63;
  const int e = lane & 31, h = lane >> 5;
  const int wt = wave * 32;
  const int slot = blockIdx.x*128 + wt + e;

  int4 er = erec[slot];
  const int rA = er.x, cA = er.y;

  float4 crd = coord4[rA], ccd = coord4[cA];
  float dx = crd.x-ccd.x, dy = crd.y-ccd.y, dz = crd.z-ccd.z;
  float radial = dx*dx + dy*dy + dz*dz;

  const short8* W1f = reinterpret_cast<const short8*>(W1p);
  const short8* W2f = reinterpret_cast<const short8*>(W2p);
  const short8* C1f = reinterpret_cast<const short8*>(C1p);

  union U4 { uint u[4]; short8 s; };

  // GEMM1: bias folded at k=131; sequential over mt; output packed into uw[16]
  uint uw[16];
  {
    short8 bf[9];
    #pragma unroll
    for (int kt = 0; kt < 4; ++kt)
      bf[kt] = *reinterpret_cast<const short8*>(hb + (size_t)rA*HD + kt*16 + h*8);
    #pragma unroll
    for (int kt = 0; kt < 4; ++kt)
      bf[4+kt] = *reinterpret_cast<const short8*>(hb + (size_t)cA*HD + kt*16 + h*8);
    short8 t8 = {0,0,0,0,0,0,0,0};
    if (h == 0){
      t8[0] = (short)f2b(radial);
      t8[1] = (short)f2b(__int_as_float(er.z));
      t8[2] = (short)f2b(__int_as_float(er.w));
      t8[3] = (short)0x3F80;   // 1.0 -> pairs with b1 packed at k=131
    }
    bf[8] = t8;

    #pragma unroll 1
    for (int mt = 0; mt < 2; ++mt){
      f32x16 a;
      #pragma unroll
      for (int r = 0; r < 16; ++r) a[r] = 0.0f;
      #pragma unroll
      for (int kt = 0; kt < 9; ++kt)
        a = __builtin_amdgcn_mfma_f32_32x32x16_bf16(W1f[(kt*2+mt)*64 + lane], bf[kt], a, 0,0,0);
      #pragma unroll
      for (int s = 0; s < 8; ++s)
        uw[mt*8 + s] = pk2(silu_f(a[2*s]), silu_f(a[2*s+1]));
    }
  }

  // GEMM2: m = silu(X1 @ W2 + b2); B-frag = uw words directly (pi-packed W2)
  uint uw2[16];
  #pragma unroll 1
  for (int mt = 0; mt < 2; ++mt){
    f32x16 a;
    #pragma unroll
    for (int q = 0; q < 4; ++q){
      f32x4 bq = *reinterpret_cast<const f32x4*>(b2 + mt*32 + q*8 + h*4);
      #pragma unroll
      for (int r = 0; r < 4; ++r) a[4*q+r] = bq[r];
    }
    #pragma unroll
    for (int kt = 0; kt < 4; ++kt){
      U4 t; t.u[0]=uw[kt*4+0]; t.u[1]=uw[kt*4+1]; t.u[2]=uw[kt*4+2]; t.u[3]=uw[kt*4+3];
      a = __builtin_amdgcn_mfma_f32_32x32x16_bf16(W2f[(kt*2+mt)*64 + lane], t.s, a, 0,0,0);
    }
    #pragma unroll
    for (int s = 0; s < 8; ++s)
      uw2[mt*8 + s] = pk2(silu_f(a[2*s]), silu_f(a[2*s+1]));
  }

  // write m to LDS (for segmented sum); row = 32 uints, stride 34
  const int wrow = (wt + e)*34 + h*16;
  #pragma unroll
  for (int t = 0; t < 8; ++t)
    *reinterpret_cast<uint2v*>(&XMT[wrow + 2*t]) = (uint2v){uw2[2*t], uw2[2*t+1]};

  // GEMM3: X3 = silu(m @ cW1 + cb1); w = X3 @ cW2 ; B-frag = uw2 words directly
  float pw = 0.0f;
  #pragma unroll 1
  for (int mt = 0; mt < 2; ++mt){
    f32x16 a;
    #pragma unroll
    for (int q = 0; q < 4; ++q){
      f32x4 bq = *reinterpret_cast<const f32x4*>(cb1 + mt*32 + q*8 + h*4);
      #pragma unroll
      for (int r = 0; r < 4; ++r) a[4*q+r] = bq[r];
    }
    #pragma unroll
    for (int kt = 0; kt < 4; ++kt){
      U4 t; t.u[0]=uw2[kt*4+0]; t.u[1]=uw2[kt*4+1]; t.u[2]=uw2[kt*4+2]; t.u[3]=uw2[kt*4+3];
      a = __builtin_amdgcn_mfma_f32_32x32x16_bf16(C1f[(kt*2+mt)*64 + lane], t.s, a, 0,0,0);
    }
    #pragma unroll
    for (int q = 0; q < 4; ++q){
      f32x4 cwq = *reinterpret_cast<const f32x4*>(cw2 + mt*32 + q*8 + h*4);
      #pragma unroll
      for (int r = 0; r < 4; ++r) pw += silu_f(a[4*q+r]) * cwq[r];
    }
  }
  pw += __shfl_xor(pw, 32);
  if (h == 0){
    f32x4 t = {dx*pw, dy*pw, dz*pw, 0.0f};
    *reinterpret_cast<f32x4*>(&TRL[(wt + e)*4]) = t;
  }

  // per-wave segmented sum over 32 CSR-sorted edges -> atomic flush
  // lane j reads feature j of edge i at ushort offset (wt+i)*68 + soff(j)
  const int j = lane;
  const int soff = (((j>>5)*8 + ((j>>3)&3)*2 + ((j>>1)&1)) + ((j>>2)&1)*16)*2 + (j&1);
  const ushort* mvals = reinterpret_cast<const ushort*>(XMT);
  float sum = 0.f, ts = 0.f;
  int rcur = __builtin_amdgcn_readlane(rA, 0);
  #pragma unroll
  for (int i = 0; i < 32; ++i){
    sum += b2f(mvals[(wt + i)*68 + soff]);
    if (lane < 3) ts += TRL[(wt + i)*4 + lane];
    int rnext = (i < 31) ? __builtin_amdgcn_readlane(rA, i+1) : -1;
    if (rnext != rcur){
      atomicAdd(&aggf[(size_t)rcur*AGS + lane], sum);
      if (lane < 3) atomicAdd(&aggf[(size_t)rcur*AGS + 64 + lane], ts);
      sum = 0.f; ts = 0.f; rcur = rnext;
    }
  }
}

// ---------------- node MFMA kernel (+fused vel/coord update, +aggf re-zero) ----------------
__global__ __launch_bounds__(256) void k_node(
    const ushort* __restrict__ hb, float* __restrict__ aggf, const float* __restrict__ h_in,
    const ushort* __restrict__ nW1p, const ushort* __restrict__ nW2p, const ushort* __restrict__ vW1p,
    const float* __restrict__ nb1, const float* __restrict__ nb2,
    const float* __restrict__ vb1, const float* __restrict__ vW2, const float* __restrict__ vb2,
    const int* __restrict__ counts, float4* __restrict__ velw4, float4* __restrict__ coordw4,
    float* __restrict__ h_out, ushort* __restrict__ hb_out,
    float* __restrict__ xout, float* __restrict__ vout, int last)
{
  __shared__ __align__(16) ushort HID[64*88];
  __shared__ float VS[64];
  const int tid = threadIdx.x;
  const int wave = tid >> 6, lane = tid & 63;
  const int c = lane & 15, g = lane >> 4;
  const int wt = wave * 16;
  const int nbase = blockIdx.x * 64;
  int nA = nbase + wt + c;
  int nAc = (nA < NN) ? nA : (NN-1);

  short8 af[4];
  af[0] = *reinterpret_cast<const short8*>(hb + (size_t)nAc*HD + g*8);
  af[1] = *reinterpret_cast<const short8*>(hb + (size_t)nAc*HD + 32 + g*8);
  {
    const float* ag = aggf + (size_t)nAc*AGS;
    f32x4 q0 = *reinterpret_cast<const f32x4*>(ag + g*8);
    f32x4 q1 = *reinterpret_cast<const f32x4*>(ag + g*8 + 4);
    f32x4 q2 = *reinterpret_cast<const f32x4*>(ag + 32 + g*8);
    f32x4 q3 = *reinterpret_cast<const f32x4*>(ag + 32 + g*8 + 4);
    union FB { ushort u[8]; short8 s; };
    FB f2_, f3_;
    #pragma unroll
    for (int i = 0; i < 4; ++i){ f2_.u[i] = f2b(q0[i]); f2_.u[4+i] = f2b(q1[i]); }
    #pragma unroll
    for (int i = 0; i < 4; ++i){ f3_.u[i] = f2b(q2[i]); f3_.u[4+i] = f2b(q3[i]); }
    af[2] = f2_.s;
    af[3] = f3_.s;
  }
  const short8* N1f = reinterpret_cast<const short8*>(nW1p);
  const short8* N2f = reinterpret_cast<const short8*>(nW2p);
  const short8* V1f = reinterpret_cast<const short8*>(vW1p);

  f32x4 acc[4];
  #pragma unroll
  for (int ct = 0; ct < 4; ++ct){
    float bb = nb1[ct*16 + c];
    acc[ct] = (f32x4){bb,bb,bb,bb};
  }
  #pragma unroll
  for (int kt = 0; kt < 4; ++kt){
    #pragma unroll
    for (int ct = 0; ct < 4; ++ct){
      acc[ct] = __builtin_amdgcn_mfma_f32_16x16x32_bf16(af[kt], N1f[(kt*4+ct)*64 + lane], acc[ct], 0,0,0);
    }
  }
  #pragma unroll
  for (int ct = 0; ct < 4; ++ct){
    int col = ct*16 + c;
    #pragma unroll
    for (int r = 0; r < 4; ++r){
      HID[(wt + g*4 + r)*88 + col] = f2b(silu_f(acc[ct][r]));
    }
  }

  // v MLP (uses h only)
  f32x4 av[4];
  #pragma unroll
  for (int ct = 0; ct < 4; ++ct){
    float bb = vb1[ct*16 + c];
    av[ct] = (f32x4){bb,bb,bb,bb};
  }
  #pragma unroll
  for (int kt = 0; kt < 2; ++kt){
    #pragma unroll
    for (int ct = 0; ct < 4; ++ct){
      av[ct] = __builtin_amdgcn_mfma_f32_16x16x32_bf16(af[kt], V1f[(kt*4+ct)*64 + lane], av[ct], 0,0,0);
    }
  }
  float pw[4] = {0.f,0.f,0.f,0.f};
  #pragma unroll
  for (int ct = 0; ct < 4; ++ct){
    float vw = vW2[ct*16 + c];
    #pragma unroll
    for (int r = 0; r < 4; ++r) pw[r] += silu_f(av[ct][r]) * vw;
  }
  #pragma unroll
  for (int off = 1; off < 16; off <<= 1){
    #pragma unroll
    for (int r = 0; r < 4; ++r) pw[r] += __shfl_xor(pw[r], off, 16);
  }
  if (c == 0){
    float vbias = vb2[0];
    #pragma unroll
    for (int r = 0; r < 4; ++r) VS[wt + g*4 + r] = pw[r] + vbias;
  }

  // node MLP second layer (reads HID written by this wave only)
  short8 h0 = *reinterpret_cast<const short8*>(&HID[(wt + c)*88 + g*8]);
  short8 h1 = *reinterpret_cast<const short8*>(&HID[(wt + c)*88 + 32 + g*8]);
  f32x4 a2[4];
  #pragma unroll
  for (int ct = 0; ct < 4; ++ct){
    float bb = nb2[ct*16 + c];
    a2[ct] = (f32x4){bb,bb,bb,bb};
  }
  #pragma unroll
  for (int ct = 0; ct < 4; ++ct)
    a2[ct] = __builtin_amdgcn_mfma_f32_16x16x32_bf16(h0, N2f[(0*4+ct)*64 + lane], a2[ct], 0,0,0);
  #pragma unroll
  for (int ct = 0; ct < 4; ++ct)
    a2[ct] = __builtin_amdgcn_mfma_f32_16x16x32_bf16(h1, N2f[(1*4+ct)*64 + lane], a2[ct], 0,0,0);
  #pragma unroll
  for (int ct = 0; ct < 4; ++ct){
    int col = ct*16 + c;
    #pragma unroll
    for (int r = 0; r < 4; ++r){
      int n = nbase + wt + g*4 + r;
      if (n < NN){
        size_t off = (size_t)n*HD + col;
        float v = 2.0f*h_in[off] + a2[ct][r];
        h_out[off] = v;
        hb_out[off] = f2b(v);
      }
    }
  }

  // fused vel/coord update
  __syncthreads();
  if (tid < 64){
    int n = nbase + tid;
    if (n < NN){
      float vsn = VS[tid];
      float inv = 1.0f / fmaxf((float)counts[n], 1.0f);
      const float* ag = aggf + (size_t)n*AGS + 64;
      float ax = ag[0]*inv, ay = ag[1]*inv, az = ag[2]*inv;
      float4 vv = velw4[n];
      float4 cc = coordw4[n];
      float v0 = vsn*vv.x + ax*(1.0f/7.0f);
      float v1 = vsn*vv.y + ay*(1.0f/7.0f);
      float v2 = vsn*vv.z + az*(1.0f/7.0f);
      float s = vv.w / (sqrtf(v0*v0 + v1*v1 + v2*v2) + 1e-8f);
      v0 *= s; v1 *= s; v2 *= s;
      float c0 = cc.x + v0*(1.0f/7.0f);
      float c1 = cc.y + v1*(1.0f/7.0f);
      float c2 = cc.z + v2*(1.0f/7.0f);
      if (last){
        vout[n*3+0] = v0; vout[n*3+1] = v1; vout[n*3+2] = v2;
        xout[n*3+0] = c0; xout[n*3+1] = c1; xout[n*3+2] = c2;
      } else {
        velw4[n] = make_float4(v0, v1, v2, vv.w);
        coordw4[n] = make_float4(c0, c1, c2, 0.0f);
      }
    }
  }

  // re-zero this block's aggf rows for the next layer (replaces per-layer memset)
  __syncthreads();
  int nvalid = NN - nbase; if (nvalid > 64) nvalid = 64;
  float* zb = aggf + (size_t)nbase*AGS;
  for (int idx2 = tid; idx2 < nvalid*AGS; idx2 += 256) zb[idx2] = 0.0f;
}

// ---------------- launcher ----------------
extern "C" void kernel_launch(void* const* d_in, const int* in_sizes, int n_in,
                              void* d_out, int out_size, void* d_ws, size_t ws_size,
                              hipStream_t stream)
{
  const float* his  = (const float*)d_in[0];
  const float* loc  = (const float*)d_in[1];
  const int*   edges= (const int*)d_in[2];
  const float* vel0 = (const float*)d_in[3];
  const float* eatt = (const float*)d_in[4];
  const float* embW = (const float*)d_in[5];
  const float* embB = (const float*)d_in[6];
  const float* eW1  = (const float*)d_in[7];
  const float* eB1  = (const float*)d_in[8];
  const float* eW2  = (const float*)d_in[9];
  const float* eB2  = (const float*)d_in[10];
  const float* cW1  = (const float*)d_in[11];
  const float* cB1  = (const float*)d_in[12];
  const float* cW2  = (const float*)d_in[13];
  const float* vW1  = (const float*)d_in[14];
  const float* vB1  = (const float*)d_in[15];
  const float* vW2  = (const float*)d_in[16];
  const float* vB2  = (const float*)d_in[17];
  const float* nW1  = (const float*)d_in[18];
  const float* nB1  = (const float*)d_in[19];
  const float* nW2  = (const float*)d_in[20];
  const float* nB2  = (const float*)d_in[21];
  const int* erow = edges;
  const int* ecol = edges + EE;

  char* ws = (char*)d_ws;
  size_t off = 0;
  auto alloc = [&](size_t bytes)->char*{
    char* p = ws + off;
    off = (off + bytes + 255) & ~(size_t)255;
    return p;
  };
  ushort* hb     = (ushort*)alloc((size_t)NN*HD*2);
  int*    counts = (int*)   alloc((size_t)NN*4);
  int*    cursor = (int*)   alloc((size_t)NN*4);
  int*    bsum   = (int*)   alloc(256*4);
  int*    bbase  = (int*)   alloc(256*4);
  float4* coordw4= (float4*)alloc((size_t)NN*16);
  float4* velw4  = (float4*)alloc((size_t)NN*16);
  float*  aggf   = (float*) alloc((size_t)NN*AGS*4);
  ushort* allp   = (ushort*)alloc(33792*2);
  int4*   erec   = (int4*)  alloc((size_t)EE*16);

  ushort* eW1p32 = allp;            // 9216
  ushort* eW2p32 = allp + 9216;     // 4096
  ushort* cW1p32 = allp + 13312;    // 4096
  ushort* nW1p   = allp + 17408;    // 8192
  ushort* nW2p   = allp + 25600;    // 4096
  ushort* vW1p   = allp + 29696;    // 4096

  float* xout = (float*)d_out;                    // [N,3]
  float* hout = (float*)d_out + (size_t)NN*3;     // [N,64] — doubles as fp32 h buffer
  float* vout = (float*)d_out + (size_t)NN*3 + (size_t)NN*HD; // [N,3]

  hipMemsetAsync(counts, 0, (size_t)NN*4, stream);
  hipMemsetAsync(aggf, 0, (size_t)NN*AGS*4, stream);
  k_count2<<<3125,256,0,stream>>>(erow, counts, loc, vel0, coordw4, velw4);
  k_bsum<<<196,256,0,stream>>>(counts, bsum);
  k_bscan<<<1,256,0,stream>>>(bsum, bbase);
  k_scatter<<<196,256,0,stream>>>(counts, bbase, cursor);
  k_fill<<<3125,256,0,stream>>>(erow, ecol, eatt, cursor, erec);
  k_packall<<<132,256,0,stream>>>(eW1, eB1, eW2, cW1, nW1, nW2, vW1, allp);
  k_embed<<<12500,256,0,stream>>>(his, embW, embB, hout, hb);

  for (int L = 0; L < 4; ++L){
    k_edge<<<6250,256,0,stream>>>(hb, coordw4, erec,
        eW1p32, eW2p32, cW1p32, eB2, cB1, cW2, aggf);
    k_node<<<782,256,0,stream>>>(hb, aggf, hout, nW1p, nW2p, vW1p,
        nB1, nB2, vB1, vW2, vB2, counts, velw4, coordw4,
        hout, hb, xout, vout, (L==3) ? 1 : 0);
  }
}